// Round 21
// baseline (153.507 us; speedup 1.0000x reference)
//
#include <hip/hip_runtime.h>
#include <hip/hip_bf16.h>

// SDPA, causal, b=16 t=2048 d=64. Outputs FP32: d_out = [ out | sm_qk ].
// R21: OCCUPANCY 2->3 blocks/CU (16->24 waves/CU). LDS diet to 46.6 KB:
//  - P tile single-buffered bf16 Pb[1] (T15 skew dropped - it measured NULL
//    in R12/R13). Round: stage || QKT->Pb, BAR, rowStore+PV, BAR.
//  - Vt[3]->Vt[2] (slot conflict existed only because of the skew).
//  - rowStore converts bf16->fp32 on the way out (256B contiguous bursts);
//    PV reads bf16 A-frags directly (no cvt).
//  - __launch_bounds__(512, 6) for 6 waves/SIMD (3 blocks x 2).
// Kept from R20: 8-wave blocks, row-band x col-half wave split, phase-1
// KT1=128 LDS overlay, role-split staging, Q-side-compensated QK^T,
// lgkm-only barriers, mirror-band zero-fill (1 tile/round), XCD clustering,
// pairing (c, 31-c).

#define BATCHES 16
#define SEQ 2048
#define DIM 64
#define QB 64
#define KT 64
#define KT1 128
#define NQB (SEQ / QB) /* 32 */
#define KLD 72
#define VLD 72
#define PBLD 72

#define BAR() do { asm volatile("s_waitcnt lgkmcnt(0)" ::: "memory"); \
                   __builtin_amdgcn_s_barrier(); } while (0)

typedef __attribute__((ext_vector_type(8))) short bf16x8;
typedef __attribute__((ext_vector_type(4))) short short4v;
typedef __attribute__((ext_vector_type(4))) float f32x4;

static __device__ __forceinline__ short f2bf(float f) {
    return __builtin_bit_cast(short, __float2bfloat16(f));
}
static __device__ __forceinline__ float bf2f(short s) {
    unsigned int u = ((unsigned int)(unsigned short)s) << 16;
    return __builtin_bit_cast(float, u);
}
static __device__ __forceinline__ void split8(f32x4 a, f32x4 b, float sc,
                                              bf16x8& hh, bf16x8& ll) {
#pragma unroll
    for (int e = 0; e < 4; ++e) {
        float x = a[e] * sc; short hb = f2bf(x);
        hh[e] = hb; ll[e] = f2bf(x - bf2f(hb));
    }
#pragma unroll
    for (int e = 0; e < 4; ++e) {
        float x = b[e] * sc; short hb = f2bf(x);
        hh[4 + e] = hb; ll[4 + e] = f2bf(x - bf2f(hb));
    }
}

// LDS (bytes): Khi[2] 18432 @0 | Vt[2] 18432 @18432 | Pb[1] 9216 @36864
// | lS 512 @46080 = 46592 total -> 3 blocks/CU. Phase-1 K1[2] 36864 overlays @0.
#define SMEM_BYTES 46592

__global__ __launch_bounds__(512, 6) void sdpa_fused(
    const float* __restrict__ Qg, const float* __restrict__ Kg,
    const float* __restrict__ Vg, float* __restrict__ Og, float* __restrict__ Pg)
{
    const int i = blockIdx.x;
    const int g = i & 7;
    const int j = i >> 3;             // 0..63
    const int b = 2 * g + (j >> 5);
    const int jj = j & 31;
    const int qb = (j < 32) ? jj : (31 - jj);   // sum-balanced pairing
    const int q0 = qb * QB;

    const int tid = threadIdx.x;
    const int lane = tid & 63;
    const int wave = tid >> 6;        // 0..7
    const int wr = wave & 3;          // row band: rows wr*16..wr*16+15
    const int h  = wave >> 2;         // col half
    const int lo = lane & 15;
    const int hi = lane >> 4;
    const bool kStager = (wave < 4);
    const int stid = kStager ? tid : (tid - 256);
    const int sr = stid >> 4;
    const int sc_ = (stid & 15) * 4;
    const int vr = (stid >> 4) * 4;
    // phase-1 staging (all 512 threads): rows s1r+32*ii, col s1c
    const int s1r = tid >> 4;         // 0..31
    const int s1c = (tid & 15) * 4;

    __shared__ __align__(16) char smem[SMEM_BYTES];
    short (*Khi)[KT * KLD]  = reinterpret_cast<short (*)[KT * KLD]>(smem);            // [2]
    short (*Vt)[DIM * VLD]  = reinterpret_cast<short (*)[DIM * VLD]>(smem + 18432);   // [2]
    short* Pb               = reinterpret_cast<short*>(smem + 36864);                 // [QB*PBLD]
    float (*lS)[QB]         = reinterpret_cast<float (*)[QB]>(smem + 46080);          // [2]
    short (*K1)[KT1 * KLD]  = reinterpret_cast<short (*)[KT1 * KLD]>(smem);           // [2] overlay

    const float* qB = Qg + (size_t)b * SEQ * DIM;
    const float* kB = Kg + (size_t)b * SEQ * DIM;
    const float* vB = Vg + (size_t)b * SEQ * DIM;

    bf16x8 qa0h, qa0l, qa1h, qa1l;
    {
        const float* qr = &qB[(size_t)(q0 + wr * 16 + lo) * DIM + hi * 8];
        split8(*(const f32x4*)qr,        *(const f32x4*)(qr + 4),  0.125f, qa0h, qa0l);
        split8(*(const f32x4*)(qr + 32), *(const f32x4*)(qr + 36), 0.125f, qa1h, qa1l);
    }

    const int nkt = qb + 1;

    // mirror-band zero-fill coords: band (31-qb) of our own batch
    const int r16z = tid >> 4;        // 0..31
    const int c4z = (tid & 15) * 4;
    float* zrow0 = &Pg[((size_t)(b * SEQ) + (NQB - 1 - qb) * QB + r16z) * SEQ + c4z];
    float* zrow1 = zrow0 + (size_t)32 * SEQ;

    // ============ phase 1: l partial sums, KT1=128 per round ============
    float rl[4] = {0.f, 0.f, 0.f, 0.f};
    {
        const int nkt1 = (nkt + 1) >> 1;        // 128-wide rounds
        auto loadK1 = [&](f32x4* kp, int t) {
#pragma unroll
            for (int ii = 0; ii < 4; ++ii)
                kp[ii] = *(const f32x4*)&kB[(size_t)(t * KT1 + s1r + 32 * ii) * DIM + s1c];
        };
        auto stageK1 = [&](int buf, const f32x4* kp) {
#pragma unroll
            for (int ii = 0; ii < 4; ++ii) {
                short4v hh;
#pragma unroll
                for (int e = 0; e < 4; ++e) hh[e] = f2bf(kp[ii][e]);
                *(short4v*)&K1[buf][(s1r + 32 * ii) * KLD + s1c] = hh;
            }
        };
        f32x4 kp[4];
        loadK1(kp, 0);
        stageK1(0, kp);
        if (nkt1 > 1) loadK1(kp, 1);
        BAR();
        const int bandMax = q0 + wr * 16 + 15;  // wave-uniform
        for (int t = 0; t < nkt1; ++t) {
            const int cur = t & 1;
            if (t + 1 < nkt1) {
                stageK1(cur ^ 1, kp);
                if (t + 2 < nkt1) loadK1(kp, t + 2);
            }
            const int base = t * KT1;
#pragma unroll
            for (int nn = 0; nn < 4; ++nn) {
                const int n = 4 * h + nn;       // col group 0..7 in the 128-tile
                const int cbase = base + 16 * n;
                if (cbase > bandMax) continue;  // wave-uniform skip
                bf16x8 kh0 = *(const bf16x8*)&K1[cur][(16 * n + lo) * KLD + hi * 8];
                bf16x8 kh1 = *(const bf16x8*)&K1[cur][(16 * n + lo) * KLD + 32 + hi * 8];
                f32x4 acc = {0.f, 0.f, 0.f, 0.f};
                __builtin_amdgcn_s_setprio(1);
                acc = __builtin_amdgcn_mfma_f32_16x16x32_bf16(qa0h, kh0, acc, 0, 0, 0);
                acc = __builtin_amdgcn_mfma_f32_16x16x32_bf16(qa1h, kh1, acc, 0, 0, 0);
                __builtin_amdgcn_s_setprio(0);
                if (cbase + 15 <= q0 + wr * 16) {   // fully unmasked (wave-uniform)
#pragma unroll
                    for (int jx = 0; jx < 4; ++jx) rl[jx] += __expf(acc[jx]);
                } else {
                    const int col = cbase + lo;
#pragma unroll
                    for (int jx = 0; jx < 4; ++jx)
                        if (col <= q0 + wr * 16 + hi * 4 + jx) rl[jx] += __expf(acc[jx]);
                }
            }
            BAR();
        }
    }
    // merge the two col-half partials -> il
#pragma unroll
    for (int m = 1; m <= 8; m <<= 1)
#pragma unroll
        for (int jx = 0; jx < 4; ++jx) rl[jx] += __shfl_xor(rl[jx], m, 16);
    if (lo == 0) {
#pragma unroll
        for (int jx = 0; jx < 4; ++jx)
            lS[h][wr * 16 + hi * 4 + jx] = rl[jx];
    }
    BAR();
    float il[4];
#pragma unroll
    for (int jx = 0; jx < 4; ++jx) {
        const int row = wr * 16 + hi * 4 + jx;
        il[jx] = 1.0f / (lS[0][row] + lS[1][row]);
    }
    BAR();   // all waves done reading lS before phase 2 overwrites smem

    // ===== phase 2: stage || QKT -> Pb(bf16), BAR, rowStore+PV, BAR =====
    const int n0 = 2 * h;
    f32x4 o2[2];
#pragma unroll
    for (int nn = 0; nn < 2; ++nn) { o2[nn][0] = 0.f; o2[nn][1] = 0.f; o2[nn][2] = 0.f; o2[nn][3] = 0.f; }

    auto loadK = [&](f32x4* kp, int kt) {
#pragma unroll
        for (int ii = 0; ii < 4; ++ii)
            kp[ii] = *(const f32x4*)&kB[(size_t)(kt * KT + sr + 16 * ii) * DIM + sc_];
    };
    auto loadV = [&](f32x4* vp, int kt) {
#pragma unroll
        for (int ii = 0; ii < 4; ++ii)
            vp[ii] = *(const f32x4*)&vB[(size_t)(kt * KT + vr + ii) * DIM + sc_];
    };
    auto stageKhi = [&](int buf, const f32x4* kp) {
#pragma unroll
        for (int ii = 0; ii < 4; ++ii) {
            short4v hh;
#pragma unroll
            for (int e = 0; e < 4; ++e) hh[e] = f2bf(kp[ii][e]);
            *(short4v*)&Khi[buf][(sr + 16 * ii) * KLD + sc_] = hh;
        }
    };
    auto stageVt = [&](int buf, const f32x4* vp) {
#pragma unroll
        for (int e = 0; e < 4; ++e) {
            short4v tv;
#pragma unroll
            for (int ii = 0; ii < 4; ++ii) tv[ii] = f2bf(vp[ii][e]);
            *(short4v*)&Vt[buf][(sc_ + e) * VLD + vr] = tv;
        }
    };
    // coalesced P row-store: 8 rows/wave, bf16->f32 cvt, 256B bursts
    auto rowStore = [&](int kt) {
        float* dstb = &Pg[((size_t)(b * SEQ) + q0 + wave * 8) * SEQ + kt * KT + lane];
#pragma unroll
        for (int rr = 0; rr < 8; ++rr)
            dstb[(size_t)rr * SEQ] = bf2f(Pb[(wave * 8 + rr) * PBLD + lane]);
    };
    // PV from Pb (bf16 direct) against Vt[vbuf]
    auto pvStep = [&](int vbuf) {
        bf16x8 pa0 = *(const bf16x8*)&Pb[(wr * 16 + lo) * PBLD + hi * 8];
        bf16x8 pa1 = *(const bf16x8*)&Pb[(wr * 16 + lo) * PBLD + 32 + hi * 8];
        __builtin_amdgcn_s_setprio(1);
#pragma unroll
        for (int nn = 0; nn < 2; ++nn) {
            const int n = n0 + nn;
            bf16x8 vb0 = *(const bf16x8*)&Vt[vbuf][(16 * n + lo) * VLD + hi * 8];
            bf16x8 vb1 = *(const bf16x8*)&Vt[vbuf][(16 * n + lo) * VLD + 32 + hi * 8];
            o2[nn] = __builtin_amdgcn_mfma_f32_16x16x32_bf16(pa0, vb0, o2[nn], 0, 0, 0);
            o2[nn] = __builtin_amdgcn_mfma_f32_16x16x32_bf16(pa1, vb1, o2[nn], 0, 0, 0);
        }
        __builtin_amdgcn_s_setprio(0);
    };

    {
        f32x4 kp[4], vp[4];
        if (kStager) {
            loadK(kp, 0); stageKhi(0, kp);
            if (nkt > 1) loadK(kp, 1);
        } else {
            loadV(vp, 0); stageVt(0, vp);
            if (nkt > 1) loadV(vp, 1);
        }
        BAR();

        for (int kt = 0; kt < nkt; ++kt) {
            const int cur = kt & 1;
            // mirror-band zero tile (1/round, kt<qb): 2 stores/thread
            if (kt < qb) {
                const int zt = (NQB - qb) + kt;
                const f32x4 zv = {0.f, 0.f, 0.f, 0.f};
                *(f32x4*)&zrow0[zt * KT] = zv;
                *(f32x4*)&zrow1[zt * KT] = zv;
            }
            // stage next tile into slot cur^1 (overlaps QKT below)
            if (kt + 1 < nkt) {
                if (kStager) {
                    stageKhi(cur ^ 1, kp);
                    if (kt + 2 < nkt) loadK(kp, kt + 2);
                } else {
                    stageVt(cur ^ 1, vp);
                    if (kt + 2 < nkt) loadV(vp, kt + 2);
                }
            }
            // QKT(kt) (Q-side compensated): P = exp(S)*il -> Pb (bf16)
#pragma unroll
            for (int nn = 0; nn < 2; ++nn) {
                const int n = n0 + nn;
                const bool fm = (kt == qb) && (n > wr);   // wave-uniform
                f32x4 acc = {0.f, 0.f, 0.f, 0.f};
                if (!fm) {
                    bf16x8 kh0 = *(const bf16x8*)&Khi[cur][(16 * n + lo) * KLD + hi * 8];
                    bf16x8 kh1 = *(const bf16x8*)&Khi[cur][(16 * n + lo) * KLD + 32 + hi * 8];
                    __builtin_amdgcn_s_setprio(1);
                    acc = __builtin_amdgcn_mfma_f32_16x16x32_bf16(qa0h, kh0, acc, 0, 0, 0);
                    acc = __builtin_amdgcn_mfma_f32_16x16x32_bf16(qa1h, kh1, acc, 0, 0, 0);
                    acc = __builtin_amdgcn_mfma_f32_16x16x32_bf16(qa0l, kh0, acc, 0, 0, 0);
                    acc = __builtin_amdgcn_mfma_f32_16x16x32_bf16(qa1l, kh1, acc, 0, 0, 0);
                    __builtin_amdgcn_s_setprio(0);
                }
                const int col = 16 * n + lo;
#pragma unroll
                for (int jx = 0; jx < 4; ++jx) {
                    const int row = wr * 16 + hi * 4 + jx;
                    const float p = (!fm && (kt < qb || col <= row)) ? __expf(acc[jx]) * il[jx] : 0.f;
                    Pb[row * PBLD + col] = f2bf(p);
                }
            }
            BAR();      // Pb visible to all waves (and stage writes retired)
            rowStore(kt);
            pvStep(cur);
            BAR();      // readers done before next round's stage/QKT overwrite
        }
    }

    // ---- O (already normalized; own col half), fp32 ----
    {
        float* og = &Og[((size_t)(b * SEQ) + q0 + wr * 16 + hi * 4) * DIM + lo];
#pragma unroll
        for (int jx = 0; jx < 4; ++jx)
#pragma unroll
            for (int nn = 0; nn < 2; ++nn)
                og[jx * DIM + (n0 + nn) * 16] = o2[nn][jx];
    }
}

extern "C" void kernel_launch(void* const* d_in, const int* in_sizes, int n_in,
                              void* d_out, int out_size, void* d_ws, size_t ws_size,
                              hipStream_t stream) {
    const float* q = (const float*)d_in[0];
    const float* k = (const float*)d_in[1];
    const float* v = (const float*)d_in[2];
    float* out  = (float*)d_out;                        // [B,T,D] fp32
    float* smqk = out + (size_t)BATCHES * SEQ * DIM;    // [B,T,T] fp32

    sdpa_fused<<<NQB * BATCHES, 512, 0, stream>>>(q, k, v, out, smqk);
}

// Round 22
// 93.308 us; speedup vs baseline: 1.6452x; 1.6452x over previous
//
#include <hip/hip_runtime.h>
#include <hip/hip_bf16.h>

// SDPA, causal, b=16 t=2048 d=64. Outputs FP32: d_out = [ out | sm_qk ].
// R22 = R20 (the 95.5us best; R21's 3-block experiment reverted -- VGPR
// spills, +86MB scratch writes) + VECTORIZED P STORES: rowStore now issues
// 2x f32x4 per lane (1KB/wave-instruction, fill-kernel width) instead of 8
// scalar dwords (256B/instr). R21 PMC showed phase-2 sustains only ~5.7
// B/cyc/CU of stores vs the fill's 11.4 -- store ISSUE rate is the suspect.
// R20 base: 8-wave blocks; phase-1 KT1=128 LDS overlay; T15 pipeline
// (rowStore+PV of kt-1 overlap QKT of kt); role-split staging; Q-side-
// compensated QK^T; fp32 Pf[2]; lgkm-only barriers; mirror-band zero-fill
// (1 tile/round, no tail); XCD clustering; pairing (c, 31-c).

#define BATCHES 16
#define SEQ 2048
#define DIM 64
#define QB 64
#define KT 64
#define KT1 128
#define NQB (SEQ / QB) /* 32 */
#define KLD 72
#define VLD 72
#define PFLD 68

#define BAR() do { asm volatile("s_waitcnt lgkmcnt(0)" ::: "memory"); \
                   __builtin_amdgcn_s_barrier(); } while (0)

typedef __attribute__((ext_vector_type(8))) short bf16x8;
typedef __attribute__((ext_vector_type(4))) short short4v;
typedef __attribute__((ext_vector_type(4))) float f32x4;

static __device__ __forceinline__ short f2bf(float f) {
    return __builtin_bit_cast(short, __float2bfloat16(f));
}
static __device__ __forceinline__ float bf2f(short s) {
    unsigned int u = ((unsigned int)(unsigned short)s) << 16;
    return __builtin_bit_cast(float, u);
}
static __device__ __forceinline__ void split8(f32x4 a, f32x4 b, float sc,
                                              bf16x8& hh, bf16x8& ll) {
#pragma unroll
    for (int e = 0; e < 4; ++e) {
        float x = a[e] * sc; short hb = f2bf(x);
        hh[e] = hb; ll[e] = f2bf(x - bf2f(hb));
    }
#pragma unroll
    for (int e = 0; e < 4; ++e) {
        float x = b[e] * sc; short hb = f2bf(x);
        hh[4 + e] = hb; ll[4 + e] = f2bf(x - bf2f(hb));
    }
}

// LDS (bytes): Khi 18432 @0 | Vt 27648 @18432 | Pf 34816 @46080 | lS 512 @80896
// = 81408 total (2 blocks/CU). Phase-1 K1[2] 36864 overlays @0.
#define SMEM_BYTES 81408

__global__ __launch_bounds__(512, 2) void sdpa_fused(
    const float* __restrict__ Qg, const float* __restrict__ Kg,
    const float* __restrict__ Vg, float* __restrict__ Og, float* __restrict__ Pg)
{
    const int i = blockIdx.x;
    const int g = i & 7;
    const int j = i >> 3;             // 0..63
    const int b = 2 * g + (j >> 5);
    const int jj = j & 31;
    const int qb = (j < 32) ? jj : (31 - jj);   // sum-balanced pairing
    const int q0 = qb * QB;

    const int tid = threadIdx.x;
    const int lane = tid & 63;
    const int wave = tid >> 6;        // 0..7
    const int wr = wave & 3;          // row band: rows wr*16..wr*16+15
    const int h  = wave >> 2;         // col half
    const int lo = lane & 15;
    const int hi = lane >> 4;
    const bool kStager = (wave < 4);
    const int stid = kStager ? tid : (tid - 256);
    const int sr = stid >> 4;
    const int sc_ = (stid & 15) * 4;
    const int vr = (stid >> 4) * 4;
    // phase-1 staging (all 512 threads): rows s1r+32*ii, col s1c
    const int s1r = tid >> 4;         // 0..31
    const int s1c = (tid & 15) * 4;

    __shared__ __align__(16) char smem[SMEM_BYTES];
    short (*Khi)[KT * KLD]  = reinterpret_cast<short (*)[KT * KLD]>(smem);            // [2]
    short (*Vt)[DIM * VLD]  = reinterpret_cast<short (*)[DIM * VLD]>(smem + 18432);   // [3]
    float (*Pf)[QB * PFLD]  = reinterpret_cast<float (*)[QB * PFLD]>(smem + 46080);   // [2]
    float (*lS)[QB]         = reinterpret_cast<float (*)[QB]>(smem + 80896);          // [2]
    short (*K1)[KT1 * KLD]  = reinterpret_cast<short (*)[KT1 * KLD]>(smem);           // [2] overlay

    const float* qB = Qg + (size_t)b * SEQ * DIM;
    const float* kB = Kg + (size_t)b * SEQ * DIM;
    const float* vB = Vg + (size_t)b * SEQ * DIM;

    bf16x8 qa0h, qa0l, qa1h, qa1l;
    {
        const float* qr = &qB[(size_t)(q0 + wr * 16 + lo) * DIM + hi * 8];
        split8(*(const f32x4*)qr,        *(const f32x4*)(qr + 4),  0.125f, qa0h, qa0l);
        split8(*(const f32x4*)(qr + 32), *(const f32x4*)(qr + 36), 0.125f, qa1h, qa1l);
    }

    const int nkt = qb + 1;

    // mirror-band zero-fill coords: band (31-qb) of our own batch
    const int r16z = tid >> 4;        // 0..31
    const int c4z = (tid & 15) * 4;
    float* zrow0 = &Pg[((size_t)(b * SEQ) + (NQB - 1 - qb) * QB + r16z) * SEQ + c4z];
    float* zrow1 = zrow0 + (size_t)32 * SEQ;

    // ============ phase 1: l partial sums, KT1=128 per round ============
    float rl[4] = {0.f, 0.f, 0.f, 0.f};
    {
        const int nkt1 = (nkt + 1) >> 1;        // 128-wide rounds
        auto loadK1 = [&](f32x4* kp, int t) {
#pragma unroll
            for (int ii = 0; ii < 4; ++ii)
                kp[ii] = *(const f32x4*)&kB[(size_t)(t * KT1 + s1r + 32 * ii) * DIM + s1c];
        };
        auto stageK1 = [&](int buf, const f32x4* kp) {
#pragma unroll
            for (int ii = 0; ii < 4; ++ii) {
                short4v hh;
#pragma unroll
                for (int e = 0; e < 4; ++e) hh[e] = f2bf(kp[ii][e]);
                *(short4v*)&K1[buf][(s1r + 32 * ii) * KLD + s1c] = hh;
            }
        };
        f32x4 kp[4];
        loadK1(kp, 0);
        stageK1(0, kp);
        if (nkt1 > 1) loadK1(kp, 1);
        BAR();
        const int bandMax = q0 + wr * 16 + 15;  // wave-uniform
        for (int t = 0; t < nkt1; ++t) {
            const int cur = t & 1;
            if (t + 1 < nkt1) {
                stageK1(cur ^ 1, kp);
                if (t + 2 < nkt1) loadK1(kp, t + 2);
            }
            const int base = t * KT1;
#pragma unroll
            for (int nn = 0; nn < 4; ++nn) {
                const int n = 4 * h + nn;       // col group 0..7 in the 128-tile
                const int cbase = base + 16 * n;
                if (cbase > bandMax) continue;  // wave-uniform skip
                bf16x8 kh0 = *(const bf16x8*)&K1[cur][(16 * n + lo) * KLD + hi * 8];
                bf16x8 kh1 = *(const bf16x8*)&K1[cur][(16 * n + lo) * KLD + 32 + hi * 8];
                f32x4 acc = {0.f, 0.f, 0.f, 0.f};
                __builtin_amdgcn_s_setprio(1);
                acc = __builtin_amdgcn_mfma_f32_16x16x32_bf16(qa0h, kh0, acc, 0, 0, 0);
                acc = __builtin_amdgcn_mfma_f32_16x16x32_bf16(qa1h, kh1, acc, 0, 0, 0);
                __builtin_amdgcn_s_setprio(0);
                if (cbase + 15 <= q0 + wr * 16) {   // fully unmasked (wave-uniform)
#pragma unroll
                    for (int jx = 0; jx < 4; ++jx) rl[jx] += __expf(acc[jx]);
                } else {
                    const int col = cbase + lo;
#pragma unroll
                    for (int jx = 0; jx < 4; ++jx)
                        if (col <= q0 + wr * 16 + hi * 4 + jx) rl[jx] += __expf(acc[jx]);
                }
            }
            BAR();
        }
    }
    // merge the two col-half partials -> il
#pragma unroll
    for (int m = 1; m <= 8; m <<= 1)
#pragma unroll
        for (int jx = 0; jx < 4; ++jx) rl[jx] += __shfl_xor(rl[jx], m, 16);
    if (lo == 0) {
#pragma unroll
        for (int jx = 0; jx < 4; ++jx)
            lS[h][wr * 16 + hi * 4 + jx] = rl[jx];
    }
    BAR();
    float il[4];
#pragma unroll
    for (int jx = 0; jx < 4; ++jx) {
        const int row = wr * 16 + hi * 4 + jx;
        il[jx] = 1.0f / (lS[0][row] + lS[1][row]);
    }
    BAR();   // all waves done reading lS before phase 2 overwrites smem

    // ===== phase 2: P -> Pf (fp32 LDS), vectorized row-store + PV pipelined ==
    const int n0 = 2 * h;
    f32x4 o2[2];
#pragma unroll
    for (int nn = 0; nn < 2; ++nn) { o2[nn][0] = 0.f; o2[nn][1] = 0.f; o2[nn][2] = 0.f; o2[nn][3] = 0.f; }

    auto loadK = [&](f32x4* kp, int kt) {
#pragma unroll
        for (int ii = 0; ii < 4; ++ii)
            kp[ii] = *(const f32x4*)&kB[(size_t)(kt * KT + sr + 16 * ii) * DIM + sc_];
    };
    auto loadV = [&](f32x4* vp, int kt) {
#pragma unroll
        for (int ii = 0; ii < 4; ++ii)
            vp[ii] = *(const f32x4*)&vB[(size_t)(kt * KT + vr + ii) * DIM + sc_];
    };
    auto stageKhi = [&](int buf, const f32x4* kp) {
#pragma unroll
        for (int ii = 0; ii < 4; ++ii) {
            short4v hh;
#pragma unroll
            for (int e = 0; e < 4; ++e) hh[e] = f2bf(kp[ii][e]);
            *(short4v*)&Khi[buf][(sr + 16 * ii) * KLD + sc_] = hh;
        }
    };
    auto stageVt = [&](int buf, const f32x4* vp) {
#pragma unroll
        for (int e = 0; e < 4; ++e) {
            short4v tv;
#pragma unroll
            for (int ii = 0; ii < 4; ++ii) tv[ii] = f2bf(vp[ii][e]);
            *(short4v*)&Vt[buf][(sc_ + e) * VLD + vr] = tv;
        }
    };
    // VECTORIZED P row-store: lane covers rows wave*8+{rr,rr+4}, 16B each ->
    // 2 dwordx4 instructions per wave per tile (1KB/instr, fill-kernel width)
    auto rowStore = [&](int pbuf, int kt) {
        const int rr = lane >> 4;          // 0..3
        const int cc = (lane & 15) * 4;    // 16B-aligned col offset
        float* dst0 = &Pg[((size_t)(b * SEQ) + q0 + wave * 8 + rr) * SEQ + kt * KT + cc];
        *(f32x4*)dst0 = *(const f32x4*)&Pf[pbuf][(wave * 8 + rr) * PFLD + cc];
        *(f32x4*)(dst0 + (size_t)4 * SEQ) =
            *(const f32x4*)&Pf[pbuf][(wave * 8 + 4 + rr) * PFLD + cc];
    };
    // PV from Pf[pbuf] (fp32 -> bf16 frags) against Vt[vbuf]
    auto pvStep = [&](int pbuf, int vbuf) {
        const float* pr = &Pf[pbuf][(wr * 16 + lo) * PFLD + hi * 8];
        f32x4 a = *(const f32x4*)pr, c2 = *(const f32x4*)(pr + 4);
        f32x4 d = *(const f32x4*)(pr + 32), e2 = *(const f32x4*)(pr + 36);
        bf16x8 pa0, pa1;
#pragma unroll
        for (int e = 0; e < 4; ++e) {
            pa0[e] = f2bf(a[e]); pa0[4 + e] = f2bf(c2[e]);
            pa1[e] = f2bf(d[e]); pa1[4 + e] = f2bf(e2[e]);
        }
        __builtin_amdgcn_s_setprio(1);
#pragma unroll
        for (int nn = 0; nn < 2; ++nn) {
            const int n = n0 + nn;
            bf16x8 vb0 = *(const bf16x8*)&Vt[vbuf][(16 * n + lo) * VLD + hi * 8];
            bf16x8 vb1 = *(const bf16x8*)&Vt[vbuf][(16 * n + lo) * VLD + 32 + hi * 8];
            o2[nn] = __builtin_amdgcn_mfma_f32_16x16x32_bf16(pa0, vb0, o2[nn], 0, 0, 0);
            o2[nn] = __builtin_amdgcn_mfma_f32_16x16x32_bf16(pa1, vb1, o2[nn], 0, 0, 0);
        }
        __builtin_amdgcn_s_setprio(0);
    };

    {
        f32x4 kp[4], vp[4];
        if (kStager) {
            loadK(kp, 0); stageKhi(0, kp);
            if (nkt > 1) loadK(kp, 1);
        } else {
            loadV(vp, 0); stageVt(0, vp);
            if (nkt > 1) loadV(vp, 1);
        }
        BAR();

        int vstg = 1, vprev = 2;
        for (int kt = 0; kt < nkt; ++kt) {
            const int cur = kt & 1;
            const int pcur = kt & 1;
            // mirror-band zero tile (1/round, kt<qb): 2 dwordx4/thread
            if (kt < qb) {
                const int zt = (NQB - qb) + kt;
                const f32x4 zv = {0.f, 0.f, 0.f, 0.f};
                *(f32x4*)&zrow0[zt * KT] = zv;
                *(f32x4*)&zrow1[zt * KT] = zv;
            }
            if (kt + 1 < nkt) {
                if (kStager) {
                    stageKhi(cur ^ 1, kp);
                    if (kt + 2 < nkt) loadK(kp, kt + 2);
                } else {
                    stageVt(vstg, vp);
                    if (kt + 2 < nkt) loadV(vp, kt + 2);
                }
            }
            // ---- tile kt-1: vectorized row-store + PV (inputs ready at start)
            if (kt > 0) {
                rowStore(pcur ^ 1, kt - 1);
                pvStep(pcur ^ 1, vprev);
            }
            // ---- QKT(kt) (Q-side compensated): P = exp(S)*il -> Pf[pcur] ----
#pragma unroll
            for (int nn = 0; nn < 2; ++nn) {
                const int n = n0 + nn;
                const bool fm = (kt == qb) && (n > wr);   // wave-uniform
                f32x4 acc = {0.f, 0.f, 0.f, 0.f};
                if (!fm) {
                    bf16x8 kh0 = *(const bf16x8*)&Khi[cur][(16 * n + lo) * KLD + hi * 8];
                    bf16x8 kh1 = *(const bf16x8*)&Khi[cur][(16 * n + lo) * KLD + 32 + hi * 8];
                    __builtin_amdgcn_s_setprio(1);
                    acc = __builtin_amdgcn_mfma_f32_16x16x32_bf16(qa0h, kh0, acc, 0, 0, 0);
                    acc = __builtin_amdgcn_mfma_f32_16x16x32_bf16(qa1h, kh1, acc, 0, 0, 0);
                    acc = __builtin_amdgcn_mfma_f32_16x16x32_bf16(qa0l, kh0, acc, 0, 0, 0);
                    acc = __builtin_amdgcn_mfma_f32_16x16x32_bf16(qa1l, kh1, acc, 0, 0, 0);
                    __builtin_amdgcn_s_setprio(0);
                }
                const int col = 16 * n + lo;
#pragma unroll
                for (int jx = 0; jx < 4; ++jx) {
                    const int row = wr * 16 + hi * 4 + jx;
                    const float p = (!fm && (kt < qb || col <= row)) ? __expf(acc[jx]) * il[jx] : 0.f;
                    Pf[pcur][row * PFLD + col] = p;
                }
            }
            BAR();
            vprev = (vprev == 2) ? 0 : vprev + 1;
            vstg  = (vstg  == 2) ? 0 : vstg  + 1;
        }
        // ---- epilogue: tile nkt-1 store + PV (after the loop's final BAR) ----
        {
            const int pl = (nkt - 1) & 1;
            const int vl = (nkt - 1) % 3;
            rowStore(pl, nkt - 1);
            pvStep(pl, vl);
        }
    }

    // ---- O (already normalized; own col half), fp32 ----
    {
        float* og = &Og[((size_t)(b * SEQ) + q0 + wr * 16 + hi * 4) * DIM + lo];
#pragma unroll
        for (int jx = 0; jx < 4; ++jx)
#pragma unroll
            for (int nn = 0; nn < 2; ++nn)
                og[jx * DIM + (n0 + nn) * 16] = o2[nn][jx];
    }
}

extern "C" void kernel_launch(void* const* d_in, const int* in_sizes, int n_in,
                              void* d_out, int out_size, void* d_ws, size_t ws_size,
                              hipStream_t stream) {
    const float* q = (const float*)d_in[0];
    const float* k = (const float*)d_in[1];
    const float* v = (const float*)d_in[2];
    float* out  = (float*)d_out;                        // [B,T,D] fp32
    float* smqk = out + (size_t)BATCHES * SEQ * DIM;    // [B,T,T] fp32

    sdpa_fused<<<NQB * BATCHES, 512, 0, stream>>>(q, k, v, out, smqk);
}

// Round 23
// 79.149 us; speedup vs baseline: 1.9395x; 1.1789x over previous
//
#include <hip/hip_runtime.h>
#include <hip/hip_bf16.h>

// SDPA, causal, b=16 t=2048 d=64. Outputs FP32: d_out = [ out | sm_qk ].
// R23 = R22 + PRE-CONVERTED bf16 K/V (prologue kernel -> d_ws, 8 MB):
// staging becomes pure load-8B/ds_write-8B (zero f2bf in the round loop),
// staging fetch bytes halve, prefetch regs shrink (f32x4 -> short4v).
// Rounding path identical (prologue f2bf == old in-loop f2bf) -> absmax
// must stay exactly 0.015625. Q path unchanged (one-time per block).
// R22 base: 8-wave blocks; phase-1 KT1=128 LDS overlay; T15 pipeline;
// role-split staging; Q-side-compensated QK^T; fp32 Pf[2]; vectorized
// 1KB/instr P-stores; lgkm-only barriers; mirror-band zero-fill; XCD
// clustering; pairing (c, 31-c).

#define BATCHES 16
#define SEQ 2048
#define DIM 64
#define QB 64
#define KT 64
#define KT1 128
#define NQB (SEQ / QB) /* 32 */
#define KLD 72
#define VLD 72
#define PFLD 68
#define NEL ((size_t)BATCHES * SEQ * DIM) /* 2M elems per tensor */

#define BAR() do { asm volatile("s_waitcnt lgkmcnt(0)" ::: "memory"); \
                   __builtin_amdgcn_s_barrier(); } while (0)

typedef __attribute__((ext_vector_type(8))) short bf16x8;
typedef __attribute__((ext_vector_type(4))) short short4v;
typedef __attribute__((ext_vector_type(4))) float f32x4;

static __device__ __forceinline__ short f2bf(float f) {
    return __builtin_bit_cast(short, __float2bfloat16(f));
}
static __device__ __forceinline__ float bf2f(short s) {
    unsigned int u = ((unsigned int)(unsigned short)s) << 16;
    return __builtin_bit_cast(float, u);
}
static __device__ __forceinline__ void split8(f32x4 a, f32x4 b, float sc,
                                              bf16x8& hh, bf16x8& ll) {
#pragma unroll
    for (int e = 0; e < 4; ++e) {
        float x = a[e] * sc; short hb = f2bf(x);
        hh[e] = hb; ll[e] = f2bf(x - bf2f(hb));
    }
#pragma unroll
    for (int e = 0; e < 4; ++e) {
        float x = b[e] * sc; short hb = f2bf(x);
        hh[4 + e] = hb; ll[4 + e] = f2bf(x - bf2f(hb));
    }
}

// ---------- prologue: K,V fp32 -> bf16 into d_ws (once) ----------
__global__ __launch_bounds__(256) void cvt_kv(
    const float* __restrict__ Kg, const float* __restrict__ Vg,
    short* __restrict__ KVh)
{
    const size_t idx = ((size_t)blockIdx.x * 256 + threadIdx.x) * 8;
    const float* src = (idx < NEL) ? (Kg + idx) : (Vg + (idx - NEL));
    f32x4 a = *(const f32x4*)src;
    f32x4 b = *(const f32x4*)(src + 4);
    bf16x8 r;
#pragma unroll
    for (int e = 0; e < 4; ++e) { r[e] = f2bf(a[e]); r[4 + e] = f2bf(b[e]); }
    *(bf16x8*)&KVh[idx] = r;
}

// LDS (bytes): Khi 18432 @0 | Vt 27648 @18432 | Pf 34816 @46080 | lS 512 @80896
// = 81408 total (2 blocks/CU). Phase-1 K1[2] 36864 overlays @0.
#define SMEM_BYTES 81408

__global__ __launch_bounds__(512, 2) void sdpa_fused(
    const float* __restrict__ Qg, const short* __restrict__ Khg,
    const short* __restrict__ Vhg, float* __restrict__ Og, float* __restrict__ Pg)
{
    const int i = blockIdx.x;
    const int g = i & 7;
    const int j = i >> 3;             // 0..63
    const int b = 2 * g + (j >> 5);
    const int jj = j & 31;
    const int qb = (j < 32) ? jj : (31 - jj);   // sum-balanced pairing
    const int q0 = qb * QB;

    const int tid = threadIdx.x;
    const int lane = tid & 63;
    const int wave = tid >> 6;        // 0..7
    const int wr = wave & 3;          // row band: rows wr*16..wr*16+15
    const int h  = wave >> 2;         // col half
    const int lo = lane & 15;
    const int hi = lane >> 4;
    const bool kStager = (wave < 4);
    const int stid = kStager ? tid : (tid - 256);
    const int sr = stid >> 4;
    const int sc_ = (stid & 15) * 4;
    const int vr = (stid >> 4) * 4;
    // phase-1 staging (all 512 threads): rows s1r+32*ii, col s1c
    const int s1r = tid >> 4;         // 0..31
    const int s1c = (tid & 15) * 4;

    __shared__ __align__(16) char smem[SMEM_BYTES];
    short (*Khi)[KT * KLD]  = reinterpret_cast<short (*)[KT * KLD]>(smem);            // [2]
    short (*Vt)[DIM * VLD]  = reinterpret_cast<short (*)[DIM * VLD]>(smem + 18432);   // [3]
    float (*Pf)[QB * PFLD]  = reinterpret_cast<float (*)[QB * PFLD]>(smem + 46080);   // [2]
    float (*lS)[QB]         = reinterpret_cast<float (*)[QB]>(smem + 80896);          // [2]
    short (*K1)[KT1 * KLD]  = reinterpret_cast<short (*)[KT1 * KLD]>(smem);           // [2] overlay

    const float* qB = Qg + (size_t)b * SEQ * DIM;
    const short* kB = Khg + (size_t)b * SEQ * DIM;
    const short* vB = Vhg + (size_t)b * SEQ * DIM;

    bf16x8 qa0h, qa0l, qa1h, qa1l;
    {
        const float* qr = &qB[(size_t)(q0 + wr * 16 + lo) * DIM + hi * 8];
        split8(*(const f32x4*)qr,        *(const f32x4*)(qr + 4),  0.125f, qa0h, qa0l);
        split8(*(const f32x4*)(qr + 32), *(const f32x4*)(qr + 36), 0.125f, qa1h, qa1l);
    }

    const int nkt = qb + 1;

    // mirror-band zero-fill coords: band (31-qb) of our own batch
    const int r16z = tid >> 4;        // 0..31
    const int c4z = (tid & 15) * 4;
    float* zrow0 = &Pg[((size_t)(b * SEQ) + (NQB - 1 - qb) * QB + r16z) * SEQ + c4z];
    float* zrow1 = zrow0 + (size_t)32 * SEQ;

    // ============ phase 1: l partial sums, KT1=128 per round ============
    float rl[4] = {0.f, 0.f, 0.f, 0.f};
    {
        const int nkt1 = (nkt + 1) >> 1;        // 128-wide rounds
        auto loadK1 = [&](short4v* kp, int t) {
#pragma unroll
            for (int ii = 0; ii < 4; ++ii)
                kp[ii] = *(const short4v*)&kB[(size_t)(t * KT1 + s1r + 32 * ii) * DIM + s1c];
        };
        auto stageK1 = [&](int buf, const short4v* kp) {
#pragma unroll
            for (int ii = 0; ii < 4; ++ii)
                *(short4v*)&K1[buf][(s1r + 32 * ii) * KLD + s1c] = kp[ii];
        };
        short4v kp[4];
        loadK1(kp, 0);
        stageK1(0, kp);
        if (nkt1 > 1) loadK1(kp, 1);
        BAR();
        const int bandMax = q0 + wr * 16 + 15;  // wave-uniform
        for (int t = 0; t < nkt1; ++t) {
            const int cur = t & 1;
            if (t + 1 < nkt1) {
                stageK1(cur ^ 1, kp);
                if (t + 2 < nkt1) loadK1(kp, t + 2);
            }
            const int base = t * KT1;
#pragma unroll
            for (int nn = 0; nn < 4; ++nn) {
                const int n = 4 * h + nn;       // col group 0..7 in the 128-tile
                const int cbase = base + 16 * n;
                if (cbase > bandMax) continue;  // wave-uniform skip
                bf16x8 kh0 = *(const bf16x8*)&K1[cur][(16 * n + lo) * KLD + hi * 8];
                bf16x8 kh1 = *(const bf16x8*)&K1[cur][(16 * n + lo) * KLD + 32 + hi * 8];
                f32x4 acc = {0.f, 0.f, 0.f, 0.f};
                __builtin_amdgcn_s_setprio(1);
                acc = __builtin_amdgcn_mfma_f32_16x16x32_bf16(qa0h, kh0, acc, 0, 0, 0);
                acc = __builtin_amdgcn_mfma_f32_16x16x32_bf16(qa1h, kh1, acc, 0, 0, 0);
                __builtin_amdgcn_s_setprio(0);
                if (cbase + 15 <= q0 + wr * 16) {   // fully unmasked (wave-uniform)
#pragma unroll
                    for (int jx = 0; jx < 4; ++jx) rl[jx] += __expf(acc[jx]);
                } else {
                    const int col = cbase + lo;
#pragma unroll
                    for (int jx = 0; jx < 4; ++jx)
                        if (col <= q0 + wr * 16 + hi * 4 + jx) rl[jx] += __expf(acc[jx]);
                }
            }
            BAR();
        }
    }
    // merge the two col-half partials -> il
#pragma unroll
    for (int m = 1; m <= 8; m <<= 1)
#pragma unroll
        for (int jx = 0; jx < 4; ++jx) rl[jx] += __shfl_xor(rl[jx], m, 16);
    if (lo == 0) {
#pragma unroll
        for (int jx = 0; jx < 4; ++jx)
            lS[h][wr * 16 + hi * 4 + jx] = rl[jx];
    }
    BAR();
    float il[4];
#pragma unroll
    for (int jx = 0; jx < 4; ++jx) {
        const int row = wr * 16 + hi * 4 + jx;
        il[jx] = 1.0f / (lS[0][row] + lS[1][row]);
    }
    BAR();   // all waves done reading lS before phase 2 overwrites smem

    // ===== phase 2: P -> Pf (fp32 LDS), vectorized row-store + PV pipelined ==
    const int n0 = 2 * h;
    f32x4 o2[2];
#pragma unroll
    for (int nn = 0; nn < 2; ++nn) { o2[nn][0] = 0.f; o2[nn][1] = 0.f; o2[nn][2] = 0.f; o2[nn][3] = 0.f; }

    auto loadK = [&](short4v* kp, int kt) {
#pragma unroll
        for (int ii = 0; ii < 4; ++ii)
            kp[ii] = *(const short4v*)&kB[(size_t)(kt * KT + sr + 16 * ii) * DIM + sc_];
    };
    auto loadV = [&](short4v* vp, int kt) {
#pragma unroll
        for (int ii = 0; ii < 4; ++ii)
            vp[ii] = *(const short4v*)&vB[(size_t)(kt * KT + vr + ii) * DIM + sc_];
    };
    auto stageKhi = [&](int buf, const short4v* kp) {
#pragma unroll
        for (int ii = 0; ii < 4; ++ii)
            *(short4v*)&Khi[buf][(sr + 16 * ii) * KLD + sc_] = kp[ii];
    };
    auto stageVt = [&](int buf, const short4v* vp) {
#pragma unroll
        for (int e = 0; e < 4; ++e) {   // 4x4 register transpose, no cvt
            short4v tv;
#pragma unroll
            for (int ii = 0; ii < 4; ++ii) tv[ii] = vp[ii][e];
            *(short4v*)&Vt[buf][(sc_ + e) * VLD + vr] = tv;
        }
    };
    // VECTORIZED P row-store: lane covers rows wave*8+{rr,rr+4}, 16B each
    auto rowStore = [&](int pbuf, int kt) {
        const int rr = lane >> 4;          // 0..3
        const int cc = (lane & 15) * 4;    // 16B-aligned col offset
        float* dst0 = &Pg[((size_t)(b * SEQ) + q0 + wave * 8 + rr) * SEQ + kt * KT + cc];
        *(f32x4*)dst0 = *(const f32x4*)&Pf[pbuf][(wave * 8 + rr) * PFLD + cc];
        *(f32x4*)(dst0 + (size_t)4 * SEQ) =
            *(const f32x4*)&Pf[pbuf][(wave * 8 + 4 + rr) * PFLD + cc];
    };
    // PV from Pf[pbuf] (fp32 -> bf16 frags) against Vt[vbuf]
    auto pvStep = [&](int pbuf, int vbuf) {
        const float* pr = &Pf[pbuf][(wr * 16 + lo) * PFLD + hi * 8];
        f32x4 a = *(const f32x4*)pr, c2 = *(const f32x4*)(pr + 4);
        f32x4 d = *(const f32x4*)(pr + 32), e2 = *(const f32x4*)(pr + 36);
        bf16x8 pa0, pa1;
#pragma unroll
        for (int e = 0; e < 4; ++e) {
            pa0[e] = f2bf(a[e]); pa0[4 + e] = f2bf(c2[e]);
            pa1[e] = f2bf(d[e]); pa1[4 + e] = f2bf(e2[e]);
        }
        __builtin_amdgcn_s_setprio(1);
#pragma unroll
        for (int nn = 0; nn < 2; ++nn) {
            const int n = n0 + nn;
            bf16x8 vb0 = *(const bf16x8*)&Vt[vbuf][(16 * n + lo) * VLD + hi * 8];
            bf16x8 vb1 = *(const bf16x8*)&Vt[vbuf][(16 * n + lo) * VLD + 32 + hi * 8];
            o2[nn] = __builtin_amdgcn_mfma_f32_16x16x32_bf16(pa0, vb0, o2[nn], 0, 0, 0);
            o2[nn] = __builtin_amdgcn_mfma_f32_16x16x32_bf16(pa1, vb1, o2[nn], 0, 0, 0);
        }
        __builtin_amdgcn_s_setprio(0);
    };

    {
        short4v kp[4], vp[4];
        if (kStager) {
            loadK(kp, 0); stageKhi(0, kp);
            if (nkt > 1) loadK(kp, 1);
        } else {
            loadV(vp, 0); stageVt(0, vp);
            if (nkt > 1) loadV(vp, 1);
        }
        BAR();

        int vstg = 1, vprev = 2;
        for (int kt = 0; kt < nkt; ++kt) {
            const int cur = kt & 1;
            const int pcur = kt & 1;
            // mirror-band zero tile (1/round, kt<qb): 2 dwordx4/thread
            if (kt < qb) {
                const int zt = (NQB - qb) + kt;
                const f32x4 zv = {0.f, 0.f, 0.f, 0.f};
                *(f32x4*)&zrow0[zt * KT] = zv;
                *(f32x4*)&zrow1[zt * KT] = zv;
            }
            if (kt + 1 < nkt) {
                if (kStager) {
                    stageKhi(cur ^ 1, kp);
                    if (kt + 2 < nkt) loadK(kp, kt + 2);
                } else {
                    stageVt(vstg, vp);
                    if (kt + 2 < nkt) loadV(vp, kt + 2);
                }
            }
            // ---- tile kt-1: vectorized row-store + PV (inputs ready at start)
            if (kt > 0) {
                rowStore(pcur ^ 1, kt - 1);
                pvStep(pcur ^ 1, vprev);
            }
            // ---- QKT(kt) (Q-side compensated): P = exp(S)*il -> Pf[pcur] ----
#pragma unroll
            for (int nn = 0; nn < 2; ++nn) {
                const int n = n0 + nn;
                const bool fm = (kt == qb) && (n > wr);   // wave-uniform
                f32x4 acc = {0.f, 0.f, 0.f, 0.f};
                if (!fm) {
                    bf16x8 kh0 = *(const bf16x8*)&Khi[cur][(16 * n + lo) * KLD + hi * 8];
                    bf16x8 kh1 = *(const bf16x8*)&Khi[cur][(16 * n + lo) * KLD + 32 + hi * 8];
                    __builtin_amdgcn_s_setprio(1);
                    acc = __builtin_amdgcn_mfma_f32_16x16x32_bf16(qa0h, kh0, acc, 0, 0, 0);
                    acc = __builtin_amdgcn_mfma_f32_16x16x32_bf16(qa1h, kh1, acc, 0, 0, 0);
                    acc = __builtin_amdgcn_mfma_f32_16x16x32_bf16(qa0l, kh0, acc, 0, 0, 0);
                    acc = __builtin_amdgcn_mfma_f32_16x16x32_bf16(qa1l, kh1, acc, 0, 0, 0);
                    __builtin_amdgcn_s_setprio(0);
                }
                const int col = 16 * n + lo;
#pragma unroll
                for (int jx = 0; jx < 4; ++jx) {
                    const int row = wr * 16 + hi * 4 + jx;
                    const float p = (!fm && (kt < qb || col <= row)) ? __expf(acc[jx]) * il[jx] : 0.f;
                    Pf[pcur][row * PFLD + col] = p;
                }
            }
            BAR();
            vprev = (vprev == 2) ? 0 : vprev + 1;
            vstg  = (vstg  == 2) ? 0 : vstg  + 1;
        }
        // ---- epilogue: tile nkt-1 store + PV (after the loop's final BAR) ----
        {
            const int pl = (nkt - 1) & 1;
            const int vl = (nkt - 1) % 3;
            rowStore(pl, nkt - 1);
            pvStep(pl, vl);
        }
    }

    // ---- O (already normalized; own col half), fp32 ----
    {
        float* og = &Og[((size_t)(b * SEQ) + q0 + wr * 16 + hi * 4) * DIM + lo];
#pragma unroll
        for (int jx = 0; jx < 4; ++jx)
#pragma unroll
            for (int nn = 0; nn < 2; ++nn)
                og[jx * DIM + (n0 + nn) * 16] = o2[nn][jx];
    }
}

extern "C" void kernel_launch(void* const* d_in, const int* in_sizes, int n_in,
                              void* d_out, int out_size, void* d_ws, size_t ws_size,
                              hipStream_t stream) {
    const float* q = (const float*)d_in[0];
    const float* k = (const float*)d_in[1];
    const float* v = (const float*)d_in[2];
    float* out  = (float*)d_out;                        // [B,T,D] fp32
    float* smqk = out + (size_t)BATCHES * SEQ * DIM;    // [B,T,T] fp32
    short* kvh  = (short*)d_ws;                         // [2*NEL] bf16 (8 MB)

    cvt_kv<<<(int)(2 * NEL / (256 * 8)), 256, 0, stream>>>(k, v, kvh);
    sdpa_fused<<<NQB * BATCHES, 512, 0, stream>>>(q, kvh, kvh + NEL, out, smqk);
}